// Round 2
// baseline (4999.687 us; speedup 1.0000x reference)
//
#include <hip/hip_runtime.h>

// Problem constants
#define Bz 2048
#define Tz 336
#define Fz 10
#define H1 70
#define H2 21

// Layer-1 padded geometry
#define HP1 72        // padded hidden cols
#define GC1 288       // 4*HP1 gate columns
#define SP1 289       // LDS row stride for W (bank-decorrelated)
#define KT1 80        // 70 (h) + 10 (x) K rows

// Layer-2 padded geometry
#define HP2 24
#define GC2 96
#define SP2 97
#define KIN2 140
#define KT2 161       // 21 (h) + 140 (x)

__device__ __forceinline__ float sigf(float x) {
    return 1.0f / (1.0f + __expf(-x));
}
__device__ __forceinline__ float tanhfast(float x) {
    // 1 - 2/(e^{2x}+1); saturates correctly at +/-inf, NaN-free
    float t = __expf(2.0f * x);
    return 1.0f - 2.0f / (t + 1.0f);
}

// bf16 (round-to-nearest-even) helpers on raw ushort storage
__device__ __forceinline__ unsigned short f2bf(float v) {
    unsigned int u = __float_as_uint(v);
    u += 0x7FFFu + ((u >> 16) & 1u);
    return (unsigned short)(u >> 16);
}
__device__ __forceinline__ float bf2f(unsigned short s) {
    return __uint_as_float(((unsigned int)s) << 16);
}

// ---------------------------------------------------------------------------
// Layer 1: bidirectional LSTM, input F=10, hidden 70.
// Grid: 256 blocks = 2 dirs x 128 tiles of 16 batch rows. 256 threads.
// Thread map: rg = tid>>5 (8 row-groups of R=2 rows), gcg = tid&31,
// gate-cols gc = gcg + 32k, k=0..8 (288 padded cols).
// y1 output: bf16 [T][B][140]
// ---------------------------------------------------------------------------
__global__ __launch_bounds__(256) void k_lstm1(
    const float* __restrict__ x,
    const float* __restrict__ wih_f, const float* __restrict__ whh_f,
    const float* __restrict__ bih_f, const float* __restrict__ bhh_f,
    const float* __restrict__ wih_b, const float* __restrict__ whh_b,
    const float* __restrict__ bih_b, const float* __restrict__ bhh_b,
    unsigned short* __restrict__ y1)
{
    __shared__ float W_s[KT1 * SP1];   // rows 0..69: Whh^T, 70..79: Wih^T
    __shared__ float bias_s[GC1];
    __shared__ float h_s[16 * HP1];
    __shared__ float x_s[16 * Fz];
    __shared__ float g_s[16 * GC1];

    const int dir = blockIdx.x >> 7;           // 0 fwd, 1 bwd
    const int b0  = (blockIdx.x & 127) << 4;   // 16 rows
    const float* wih = dir ? wih_b : wih_f;
    const float* whh = dir ? whh_b : whh_f;
    const float* bih = dir ? bih_b : bih_f;
    const float* bhh = dir ? bhh_b : bhh_f;

    const int tid = threadIdx.x;

    // Load weights into LDS: W_s[j*SP1 + gc] = W[gate*70+c][j] (0 in pads)
    for (int e = tid; e < GC1 * KT1; e += 256) {
        int gc = e / KT1, j = e % KT1;
        int g = gc / HP1, c = gc % HP1;
        float v = 0.0f;
        if (c < H1) {
            int row = g * H1 + c;
            v = (j < H1) ? whh[row * H1 + j] : wih[row * Fz + (j - H1)];
        }
        W_s[j * SP1 + gc] = v;
    }
    for (int gc = tid; gc < GC1; gc += 256) {
        int g = gc / HP1, c = gc % HP1;
        bias_s[gc] = (c < H1) ? (bih[g * H1 + c] + bhh[g * H1 + c]) : 0.0f;
    }
    for (int e = tid; e < 16 * HP1; e += 256) h_s[e] = 0.0f;

    const int rg  = tid >> 5;
    const int gcg = tid & 31;
    const int r0  = rg * 2, r1 = r0 + 1;

    float c_reg[5];
#pragma unroll
    for (int k = 0; k < 5; ++k) c_reg[k] = 0.0f;

    float acc[2][9];

    for (int step = 0; step < Tz; ++step) {
        const int t = dir ? (Tz - 1 - step) : step;

        // stage x rows (16 x 10)
        if (tid < 16 * Fz) {
            int r = tid / Fz, f = tid % Fz;
            x_s[tid] = x[(size_t)(b0 + r) * Tz * Fz + (size_t)t * Fz + f];
        }
        __syncthreads();   // A: x_s ready; prev h_s writes visible

#pragma unroll
        for (int k = 0; k < 9; ++k) {
            float bv = bias_s[gcg + 32 * k];
            acc[0][k] = bv; acc[1][k] = bv;
        }
        // hidden part
#pragma unroll 2
        for (int j = 0; j < H1; ++j) {
            float h0 = h_s[r0 * HP1 + j];
            float h1 = h_s[r1 * HP1 + j];
            const float* wrow = &W_s[j * SP1 + gcg];
#pragma unroll
            for (int k = 0; k < 9; ++k) {
                float w = wrow[32 * k];
                acc[0][k] = fmaf(h0, w, acc[0][k]);
                acc[1][k] = fmaf(h1, w, acc[1][k]);
            }
        }
        // input part
#pragma unroll
        for (int j = 0; j < Fz; ++j) {
            float x0 = x_s[r0 * Fz + j];
            float x1 = x_s[r1 * Fz + j];
            const float* wrow = &W_s[(H1 + j) * SP1 + gcg];
#pragma unroll
            for (int k = 0; k < 9; ++k) {
                float w = wrow[32 * k];
                acc[0][k] = fmaf(x0, w, acc[0][k]);
                acc[1][k] = fmaf(x1, w, acc[1][k]);
            }
        }
        // write gate pre-activations
#pragma unroll
        for (int k = 0; k < 9; ++k) {
            g_s[r0 * GC1 + gcg + 32 * k] = acc[0][k];
            g_s[r1 * GC1 + gcg + 32 * k] = acc[1][k];
        }
        __syncthreads();   // B: g_s ready; all h_s reads done

        // epilogue: 16*80 padded cells, 5/thread, fixed (r,cc) per thread
#pragma unroll
        for (int k2 = 0; k2 < 5; ++k2) {
            int e = tid + 256 * k2;
            int r = e / 80, cc = e % 80;
            if (cc < H1) {
                float gi = g_s[r * GC1 + cc];
                float gf = g_s[r * GC1 + HP1 + cc];
                float gg = g_s[r * GC1 + 2 * HP1 + cc];
                float go = g_s[r * GC1 + 3 * HP1 + cc];
                float cn = sigf(gf) * c_reg[k2] + sigf(gi) * tanhfast(gg);
                float h  = sigf(go) * tanhfast(cn);
                c_reg[k2] = cn;
                h_s[r * HP1 + cc] = h;
                y1[(size_t)t * Bz * 140 + (size_t)(b0 + r) * 140 + dir * H1 + cc] = f2bf(h);
            }
        }
    }
}

// ---------------------------------------------------------------------------
// Layer 2: bidirectional LSTM, input 140 (bf16 from y1), hidden 21.
// Grid: 256 blocks = 2 dirs x 128 tiles of 16 rows. 256 threads.
// gc = gcg + 32k, k=0..2 (96 padded gate cols).
// y2 output: bf16 [B][T][42]
// ---------------------------------------------------------------------------
__global__ __launch_bounds__(256) void k_lstm2(
    const unsigned short* __restrict__ y1,
    const float* __restrict__ wih_f, const float* __restrict__ whh_f,
    const float* __restrict__ bih_f, const float* __restrict__ bhh_f,
    const float* __restrict__ wih_b, const float* __restrict__ whh_b,
    const float* __restrict__ bih_b, const float* __restrict__ bhh_b,
    unsigned short* __restrict__ y2)
{
    __shared__ float W_s[KT2 * SP2];     // rows 0..20: Whh^T, 21..160: Wih^T
    __shared__ float bias_s[GC2];
    __shared__ float h_s[16 * HP2];
    __shared__ float x_s[16 * KIN2];
    __shared__ float g_s[16 * GC2];

    const int dir = blockIdx.x >> 7;
    const int b0  = (blockIdx.x & 127) << 4;
    const float* wih = dir ? wih_b : wih_f;
    const float* whh = dir ? whh_b : whh_f;
    const float* bih = dir ? bih_b : bih_f;
    const float* bhh = dir ? bhh_b : bhh_f;

    const int tid = threadIdx.x;

    for (int e = tid; e < GC2 * KT2; e += 256) {
        int gc = e / KT2, j = e % KT2;
        int g = gc / HP2, c = gc % HP2;
        float v = 0.0f;
        if (c < H2) {
            int row = g * H2 + c;
            v = (j < H2) ? whh[row * H2 + j] : wih[row * KIN2 + (j - H2)];
        }
        W_s[j * SP2 + gc] = v;
    }
    for (int gc = tid; gc < GC2; gc += 256) {
        int g = gc / HP2, c = gc % HP2;
        bias_s[gc] = (c < H2) ? (bih[g * H2 + c] + bhh[g * H2 + c]) : 0.0f;
    }
    for (int e = tid; e < 16 * HP2; e += 256) h_s[e] = 0.0f;

    const int rg  = tid >> 5;
    const int gcg = tid & 31;
    const int r0  = rg * 2, r1 = r0 + 1;

    float c_reg[2];
    c_reg[0] = 0.0f; c_reg[1] = 0.0f;

    float acc[2][3];

    for (int step = 0; step < Tz; ++step) {
        const int t = dir ? (Tz - 1 - step) : step;

        // stage 16x140 bf16 input rows (contiguous 2240 bf16 = 1120 dwords)
        {
            const unsigned int* src = (const unsigned int*)
                &y1[(size_t)t * Bz * 140 + (size_t)b0 * 140];
            for (int e = tid; e < (16 * KIN2) / 2; e += 256) {
                unsigned int v = src[e];
                x_s[2 * e]     = bf2f((unsigned short)(v & 0xFFFFu));
                x_s[2 * e + 1] = bf2f((unsigned short)(v >> 16));
            }
        }
        __syncthreads();   // A

#pragma unroll
        for (int k = 0; k < 3; ++k) {
            float bv = bias_s[gcg + 32 * k];
            acc[0][k] = bv; acc[1][k] = bv;
        }
#pragma unroll 3
        for (int j = 0; j < H2; ++j) {
            float h0 = h_s[r0 * HP2 + j];
            float h1 = h_s[r1 * HP2 + j];
            const float* wrow = &W_s[j * SP2 + gcg];
#pragma unroll
            for (int k = 0; k < 3; ++k) {
                float w = wrow[32 * k];
                acc[0][k] = fmaf(h0, w, acc[0][k]);
                acc[1][k] = fmaf(h1, w, acc[1][k]);
            }
        }
#pragma unroll 4
        for (int j = 0; j < KIN2; ++j) {
            float x0 = x_s[r0 * KIN2 + j];
            float x1 = x_s[r1 * KIN2 + j];
            const float* wrow = &W_s[(H2 + j) * SP2 + gcg];
#pragma unroll
            for (int k = 0; k < 3; ++k) {
                float w = wrow[32 * k];
                acc[0][k] = fmaf(x0, w, acc[0][k]);
                acc[1][k] = fmaf(x1, w, acc[1][k]);
            }
        }
#pragma unroll
        for (int k = 0; k < 3; ++k) {
            g_s[r0 * GC2 + gcg + 32 * k] = acc[0][k];
            g_s[r1 * GC2 + gcg + 32 * k] = acc[1][k];
        }
        __syncthreads();   // B

        // epilogue: 16*24 = 384 padded cells, up to 2/thread
#pragma unroll
        for (int k2 = 0; k2 < 2; ++k2) {
            int e = tid + 256 * k2;
            if (e < 16 * HP2) {
                int r = e / HP2, cc = e % HP2;
                if (cc < H2) {
                    float gi = g_s[r * GC2 + cc];
                    float gf = g_s[r * GC2 + HP2 + cc];
                    float gg = g_s[r * GC2 + 2 * HP2 + cc];
                    float go = g_s[r * GC2 + 3 * HP2 + cc];
                    float cn = sigf(gf) * c_reg[k2] + sigf(gi) * tanhfast(gg);
                    float h  = sigf(go) * tanhfast(cn);
                    c_reg[k2] = cn;
                    h_s[r * HP2 + cc] = h;
                    y2[((size_t)(b0 + r) * Tz + t) * 42 + dir * H2 + cc] = f2bf(h);
                }
            }
        }
    }
}

// ---------------------------------------------------------------------------
// Dense head: thread per (b,t). Weights read via uniform (scalar) loads.
// y2 input: bf16 [B][T][42] (each row 42 bf16 = 21 dwords, contiguous)
// ---------------------------------------------------------------------------
__global__ __launch_bounds__(256) void k_dense(
    const unsigned short* __restrict__ y2,
    const float* __restrict__ wd1, const float* __restrict__ bd1,
    const float* __restrict__ wd2, const float* __restrict__ bd2,
    const float* __restrict__ wo,  const float* __restrict__ bo,
    float* __restrict__ out)
{
    int idx = blockIdx.x * 256 + threadIdx.x;
    if (idx >= Bz * Tz) return;
    const unsigned int* row = (const unsigned int*)&y2[(size_t)idx * 42];

    float v[42];
#pragma unroll
    for (int j = 0; j < 21; ++j) {
        unsigned int p = row[j];
        v[2 * j]     = bf2f((unsigned short)(p & 0xFFFFu));
        v[2 * j + 1] = bf2f((unsigned short)(p >> 16));
    }

    float h1[30];
#pragma unroll
    for (int o = 0; o < 30; ++o) {
        float s = bd1[o];
#pragma unroll
        for (int j = 0; j < 42; ++j) s = fmaf(v[j], wd1[o * 42 + j], s);
        h1[o] = fmaxf(s, 0.0f);
    }
    float outv = bo[0];
#pragma unroll
    for (int o = 0; o < 20; ++o) {
        float s = bd2[o];
#pragma unroll
        for (int j = 0; j < 30; ++j) s = fmaf(h1[j], wd2[o * 30 + j], s);
        outv = fmaf(fmaxf(s, 0.0f), wo[o], outv);
    }
    out[idx] = outv;
}

// ---------------------------------------------------------------------------
extern "C" void kernel_launch(void* const* d_in, const int* in_sizes, int n_in,
                              void* d_out, int out_size, void* d_ws, size_t ws_size,
                              hipStream_t stream)
{
    const float* x      = (const float*)d_in[0];
    const float* w1f_ih = (const float*)d_in[1];
    const float* w1f_hh = (const float*)d_in[2];
    const float* b1f_ih = (const float*)d_in[3];
    const float* b1f_hh = (const float*)d_in[4];
    const float* w1b_ih = (const float*)d_in[5];
    const float* w1b_hh = (const float*)d_in[6];
    const float* b1b_ih = (const float*)d_in[7];
    const float* b1b_hh = (const float*)d_in[8];
    const float* w2f_ih = (const float*)d_in[9];
    const float* w2f_hh = (const float*)d_in[10];
    const float* b2f_ih = (const float*)d_in[11];
    const float* b2f_hh = (const float*)d_in[12];
    const float* w2b_ih = (const float*)d_in[13];
    const float* w2b_hh = (const float*)d_in[14];
    const float* b2b_ih = (const float*)d_in[15];
    const float* b2b_hh = (const float*)d_in[16];
    const float* wd1    = (const float*)d_in[17];
    const float* bd1    = (const float*)d_in[18];
    const float* wd2    = (const float*)d_in[19];
    const float* bd2    = (const float*)d_in[20];
    const float* wo     = (const float*)d_in[21];
    const float* bo     = (const float*)d_in[22];
    float* out = (float*)d_out;

    // Workspace layout (bf16 intermediates):
    //   y1: [T][B][140] bf16 = 192,675,840 B
    //   y2: [B][T][42]  bf16 =  57,802,752 B
    // total = 250,478,592 B (~239 MiB)
    const size_t y1_elems = (size_t)Tz * Bz * 140;
    const size_t y2_elems = (size_t)Bz * Tz * 42;
    const size_t need = y1_elems * 2 + y2_elems * 2;
    if (ws_size < need) return;  // defensive: fail with absmax, not a fault

    unsigned short* y1 = (unsigned short*)d_ws;
    unsigned short* y2 = y1 + y1_elems;

    hipLaunchKernelGGL(k_lstm1, dim3(256), dim3(256), 0, stream,
                       x, w1f_ih, w1f_hh, b1f_ih, b1f_hh,
                       w1b_ih, w1b_hh, b1b_ih, b1b_hh, y1);
    hipLaunchKernelGGL(k_lstm2, dim3(256), dim3(256), 0, stream,
                       y1, w2f_ih, w2f_hh, b2f_ih, b2f_hh,
                       w2b_ih, w2b_hh, b2b_ih, b2b_hh, y2);
    hipLaunchKernelGGL(k_dense, dim3((Bz * Tz + 255) / 256), dim3(256), 0, stream,
                       y2, wd1, bd1, wd2, bd2, wo, bo, out);
}

// Round 3
// 1258.357 us; speedup vs baseline: 3.9732x; 3.9732x over previous
//
#include <hip/hip_runtime.h>

// Problem constants
#define Bz 2048
#define Tz 336
#define Fz 10
#define H1 70
#define H2 21

typedef __attribute__((ext_vector_type(8))) short short8;   // 8 bf16 = 4 VGPR
typedef __attribute__((ext_vector_type(4))) float float4v;  // MFMA acc

#define MFMA16(a, b, c) __builtin_amdgcn_mfma_f32_16x16x32_bf16((a), (b), (c), 0, 0, 0)

__device__ __forceinline__ float sigf(float x) {
    return 1.0f / (1.0f + __expf(-x));
}
__device__ __forceinline__ float tanhfast(float x) {
    float t = __expf(2.0f * x);
    return 1.0f - 2.0f / (t + 1.0f);
}
__device__ __forceinline__ unsigned short f2bf(float v) {
    unsigned int u = __float_as_uint(v);
    u += 0x7FFFu + ((u >> 16) & 1u);
    return (unsigned short)(u >> 16);
}
__device__ __forceinline__ float bf2f(unsigned short s) {
    return __uint_as_float(((unsigned int)s) << 16);
}

// A-fragment-order LDS offset (in shorts) for element (row m, k):
// element (m, k) lives at ((k>>3)*16 + m)*8 + (k&7)  [lane = (k>>3 within chunk)*16+m]
__device__ __forceinline__ int frag_off(int m, int k) {
    return (k >> 3) * 128 + m * 8 + (k & 7);
}

// ---------------------------------------------------------------------------
// Layer 1 (MFMA): input F=10, hidden 70. 256 blocks = 2 dir x 128 tiles(16 rows).
// GEMM per step: [16 x 96] x [96 x 320]; K: h(0..69), x(70..79), pad(80..95);
// N: gate g cols at [80g, 80g+70), pad to 80. Wave w owns gate w (tiles 5w..5w+4).
// W lives in registers as B-frags (hi+lo bf16) for all 336 steps.
// ---------------------------------------------------------------------------
__global__ __launch_bounds__(256, 1) void k_lstm1(
    const float* __restrict__ x,
    const float* __restrict__ wih_f, const float* __restrict__ whh_f,
    const float* __restrict__ bih_f, const float* __restrict__ bhh_f,
    const float* __restrict__ wih_b, const float* __restrict__ whh_b,
    const float* __restrict__ bih_b, const float* __restrict__ bhh_b,
    unsigned short* __restrict__ y1)
{
    __shared__ short hA_hi[1536];   // 96 k-slots x 16 rows, frag order (3 KB)
    __shared__ short hA_lo[1536];
    __shared__ float g_s[320 * 16]; // [col][row] fp32 gate preacts (20 KB)

    const int dir = blockIdx.x >> 7;
    const int b0  = (blockIdx.x & 127) << 4;
    const float* wih = dir ? wih_b : wih_f;
    const float* whh = dir ? whh_b : whh_f;
    const float* bih = dir ? bih_b : bih_f;
    const float* bhh = dir ? bhh_b : bhh_f;

    const int tid  = threadIdx.x;
    const int wv   = tid >> 6;        // wave = gate index (i,f,g,o)
    const int lane = tid & 63;
    const int n    = lane & 15;       // MFMA col-in-tile / row m
    const int quad = lane >> 4;

    // ---- B-fragment preload (once): B[k][col] = W[col][k], hi+lo bf16 ----
    short8 bhi[5][3], blo[5][3];
#pragma unroll
    for (int tt = 0; tt < 5; ++tt) {
#pragma unroll
        for (int q = 0; q < 3; ++q) {
#pragma unroll
            for (int j = 0; j < 8; ++j) {
                int k  = q * 32 + quad * 8 + j;
                int cc = 16 * tt + n;          // hidden unit within gate
                float v = 0.0f;
                if (cc < H1 && k < 80) {
                    int row = wv * H1 + cc;
                    v = (k < H1) ? whh[row * H1 + k] : wih[row * Fz + (k - H1)];
                }
                unsigned short hi = f2bf(v);
                unsigned short lo = f2bf(v - bf2f(hi));
                bhi[tt][q][j] = (short)hi;
                blo[tt][q][j] = (short)lo;
            }
        }
    }

    // ---- bias registers for epilogue: 3 iters x {even,odd cell} x 4 gates ----
    float breg[3][2][4];
    float cst[3][2];
#pragma unroll
    for (int it = 0; it < 3; ++it) {
        cst[it][0] = 0.0f; cst[it][1] = 0.0f;
        int p = it * 256 + tid;
        if (p < 560) {
            int c0 = (p >> 4) * 2;
#pragma unroll
            for (int g = 0; g < 4; ++g) {
                breg[it][0][g] = bih[g * H1 + c0]     + bhh[g * H1 + c0];
                breg[it][1][g] = bih[g * H1 + c0 + 1] + bhh[g * H1 + c0 + 1];
            }
        }
    }

    // ---- init LDS: zero hA (h=0, pads=0), then stage x(t0) ----
    for (int e = tid; e < 1536; e += 256) { hA_hi[e] = 0; hA_lo[e] = 0; }
    __syncthreads();
    {
        const int t0 = dir ? (Tz - 1) : 0;
        if (tid < 160) {
            int m = tid / Fz, f = tid % Fz;
            float v = x[((size_t)(b0 + m) * Tz + t0) * Fz + f];
            unsigned short hi = f2bf(v);
            unsigned short lo = f2bf(v - bf2f(hi));
            int off = frag_off(m, H1 + f);
            hA_hi[off] = (short)hi;
            hA_lo[off] = (short)lo;
        }
    }

    for (int step = 0; step < Tz; ++step) {
        const int t = dir ? (Tz - 1 - step) : step;
        __syncthreads();   // barrier1: hA (h + x) ready for this step

        // prefetch next step's x into registers (latency hidden behind MFMA)
        float xv = 0.0f;
        const int tn = dir ? (t - 1) : (t + 1);
        const bool hx = (tid < 160) && (step + 1 < Tz);
        if (hx) {
            int m = tid / Fz, f = tid % Fz;
            xv = x[((size_t)(b0 + m) * Tz + tn) * Fz + f];
        }

        // A-fragment loads (all waves read full A)
        short8 ahi[3], alo[3];
#pragma unroll
        for (int q = 0; q < 3; ++q) {
            ahi[q] = *(const short8*)&hA_hi[q * 512 + lane * 8];
            alo[q] = *(const short8*)&hA_lo[q * 512 + lane * 8];
        }

        // MFMA: per wave 5 tiles x 3 K-chunks x 3 products
        float4v acc[5];
#pragma unroll
        for (int tt = 0; tt < 5; ++tt) acc[tt] = (float4v){0.f, 0.f, 0.f, 0.f};
#pragma unroll
        for (int tt = 0; tt < 5; ++tt) {
#pragma unroll
            for (int q = 0; q < 3; ++q) {
                acc[tt] = MFMA16(ahi[q], bhi[tt][q], acc[tt]);
                acc[tt] = MFMA16(ahi[q], blo[tt][q], acc[tt]);
                acc[tt] = MFMA16(alo[q], bhi[tt][q], acc[tt]);
            }
        }
        // C store: D[row][col]: row = quad*4+reg, col = 16*tile + n
#pragma unroll
        for (int tt = 0; tt < 5; ++tt) {
            *(float4v*)&g_s[(16 * (5 * wv + tt) + n) * 16 + quad * 4] = acc[tt];
        }

        __syncthreads();   // barrier2: g_s ready; hA reads done

        // epilogue: 560 (row, col-pair) tasks; thread p -> m=p&15, c0=2*(p>>4)
#pragma unroll
        for (int it = 0; it < 3; ++it) {
            int p = it * 256 + tid;
            if (p < 560) {
                int m  = p & 15;
                int c0 = (p >> 4) * 2;
                float ge[4], go_[4];
#pragma unroll
                for (int g = 0; g < 4; ++g) ge[g]  = g_s[(80 * g + c0) * 16 + m];
#pragma unroll
                for (int g = 0; g < 4; ++g) go_[g] = g_s[(80 * g + c0 + 1) * 16 + m];

                float cn0 = sigf(ge[1] + breg[it][0][1]) * cst[it][0]
                          + sigf(ge[0] + breg[it][0][0]) * tanhfast(ge[2] + breg[it][0][2]);
                float h0  = sigf(ge[3] + breg[it][0][3]) * tanhfast(cn0);
                cst[it][0] = cn0;

                float cn1 = sigf(go_[1] + breg[it][1][1]) * cst[it][1]
                          + sigf(go_[0] + breg[it][1][0]) * tanhfast(go_[2] + breg[it][1][2]);
                float h1  = sigf(go_[3] + breg[it][1][3]) * tanhfast(cn1);
                cst[it][1] = cn1;

                unsigned short h0h = f2bf(h0), h1h = f2bf(h1);
                unsigned short h0l = f2bf(h0 - bf2f(h0h));
                unsigned short h1l = f2bf(h1 - bf2f(h1h));

                int so = frag_off(m, c0);      // even -> dword aligned
                ((unsigned int*)hA_hi)[so >> 1] = (unsigned int)h0h | ((unsigned int)h1h << 16);
                ((unsigned int*)hA_lo)[so >> 1] = (unsigned int)h0l | ((unsigned int)h1l << 16);

                size_t yi = (((size_t)t * Bz + (b0 + m)) * 140 + dir * H1 + c0);
                ((unsigned int*)y1)[yi >> 1] = (unsigned int)h0h | ((unsigned int)h1h << 16);
            }
        }
        // stage next x (writes protected from this step's A-reads by barrier2)
        if (hx) {
            int m = tid / Fz, f = tid % Fz;
            unsigned short hi = f2bf(xv);
            unsigned short lo = f2bf(xv - bf2f(hi));
            int off = frag_off(m, H1 + f);
            hA_hi[off] = (short)hi;
            hA_lo[off] = (short)lo;
        }
    }
}

// ---------------------------------------------------------------------------
// Layer 2 (MFMA): input 140 (bf16 y1), hidden 21. 256 blocks = 2 dir x 128 tiles.
// GEMM per step: [16 x 192] x [192 x 128]; K: h(0..20) in chunk0, x at 32..171,
// pad to 192. N: gate g cols at [32g, 32g+21), pad 32. Wave w owns gate w
// (tiles 2w, 2w+1). x is bf16 (no lo); h and W carry hi+lo.
// ---------------------------------------------------------------------------
__global__ __launch_bounds__(256, 1) void k_lstm2(
    const unsigned short* __restrict__ y1,
    const float* __restrict__ wih_f, const float* __restrict__ whh_f,
    const float* __restrict__ bih_f, const float* __restrict__ bhh_f,
    const float* __restrict__ wih_b, const float* __restrict__ whh_b,
    const float* __restrict__ bih_b, const float* __restrict__ bhh_b,
    unsigned short* __restrict__ y2)
{
    __shared__ short hA_hi[3072];   // 192 k-slots x 16 rows (6 KB)
    __shared__ short hA_lo[512];    // chunk0 only (h lo) (1 KB)
    __shared__ float g_s[128 * 16]; // [col][row] (8 KB)

    const int dir = blockIdx.x >> 7;
    const int b0  = (blockIdx.x & 127) << 4;
    const float* wih = dir ? wih_b : wih_f;
    const float* whh = dir ? whh_b : whh_f;
    const float* bih = dir ? bih_b : bih_f;
    const float* bhh = dir ? bhh_b : bhh_f;

    const int tid  = threadIdx.x;
    const int wv   = tid >> 6;
    const int lane = tid & 63;
    const int n    = lane & 15;
    const int quad = lane >> 4;

    // ---- B-frag preload: wave wv = gate wv, tiles {2wv, 2wv+1} ----
    short8 bhi[2][6], blo[2][6];
#pragma unroll
    for (int tt = 0; tt < 2; ++tt) {
#pragma unroll
        for (int q = 0; q < 6; ++q) {
#pragma unroll
            for (int j = 0; j < 8; ++j) {
                int k  = q * 32 + quad * 8 + j;
                int cc = 16 * tt + n;
                float v = 0.0f;
                if (cc < H2) {
                    int row = wv * H2 + cc;
                    if (k < H2)                 v = whh[row * H2 + k];
                    else if (k >= 32 && k < 172) v = wih[row * 140 + (k - 32)];
                }
                unsigned short hi = f2bf(v);
                unsigned short lo = f2bf(v - bf2f(hi));
                bhi[tt][q][j] = (short)hi;
                blo[tt][q][j] = (short)lo;
            }
        }
    }

    // ---- bias regs: cells e = tid and tid+256 (336 cells) ----
    float breg[2][4];
    float cst[2];
    cst[0] = 0.0f; cst[1] = 0.0f;
#pragma unroll
    for (int it = 0; it < 2; ++it) {
        int e = it * 256 + tid;
        if (e < 16 * H2) {
            int c = e % H2;
#pragma unroll
            for (int g = 0; g < 4; ++g)
                breg[it][g] = bih[g * H2 + c] + bhh[g * H2 + c];
        }
    }

    // ---- init: zero hA, stage x(t0) ----
    for (int e = tid; e < 3072; e += 256) hA_hi[e] = 0;
    for (int e = tid; e < 512;  e += 256) hA_lo[e] = 0;
    __syncthreads();
    {
        const int t0 = dir ? (Tz - 1) : 0;
        const unsigned int* src = (const unsigned int*)y1;
        for (int e2 = tid; e2 < 1120; e2 += 256) {
            int m = e2 / 70, xip = e2 % 70;
            unsigned int v = src[((size_t)t0 * Bz + (b0 + m)) * 70 + xip];
            int k = 32 + 2 * xip;
            ((unsigned int*)hA_hi)[frag_off(m, k) >> 1] = v;
        }
    }

    for (int step = 0; step < Tz; ++step) {
        const int t = dir ? (Tz - 1 - step) : step;
        __syncthreads();   // barrier1

        // prefetch next x (5 dwords/thread) into registers
        unsigned int xr[5];
        const int tn = dir ? (t - 1) : (t + 1);
        const bool hx = (step + 1 < Tz);
        if (hx) {
            const unsigned int* src = (const unsigned int*)y1;
#pragma unroll
            for (int i = 0; i < 5; ++i) {
                int e2 = tid + 256 * i;
                if (e2 < 1120) {
                    int m = e2 / 70, xip = e2 % 70;
                    xr[i] = src[((size_t)tn * Bz + (b0 + m)) * 70 + xip];
                }
            }
        }

        // A-frag loads
        short8 ahi[6], alo0;
#pragma unroll
        for (int q = 0; q < 6; ++q)
            ahi[q] = *(const short8*)&hA_hi[q * 512 + lane * 8];
        alo0 = *(const short8*)&hA_lo[lane * 8];

        // MFMA: per wave 2 tiles; chunk0: 3 products (h hi/lo), chunks1-5: 2
        float4v acc[2];
        acc[0] = (float4v){0.f, 0.f, 0.f, 0.f};
        acc[1] = (float4v){0.f, 0.f, 0.f, 0.f};
#pragma unroll
        for (int tt = 0; tt < 2; ++tt) {
            acc[tt] = MFMA16(ahi[0], bhi[tt][0], acc[tt]);
            acc[tt] = MFMA16(ahi[0], blo[tt][0], acc[tt]);
            acc[tt] = MFMA16(alo0,   bhi[tt][0], acc[tt]);
#pragma unroll
            for (int q = 1; q < 6; ++q) {
                acc[tt] = MFMA16(ahi[q], bhi[tt][q], acc[tt]);
                acc[tt] = MFMA16(ahi[q], blo[tt][q], acc[tt]);
            }
        }
#pragma unroll
        for (int tt = 0; tt < 2; ++tt) {
            *(float4v*)&g_s[(16 * (2 * wv + tt) + n) * 16 + quad * 4] = acc[tt];
        }

        __syncthreads();   // barrier2

        // epilogue: 336 cells
#pragma unroll
        for (int it = 0; it < 2; ++it) {
            int e = it * 256 + tid;
            if (e < 16 * H2) {
                int m = e / H2, c = e % H2;
                float gi = g_s[(c)       * 16 + m] + breg[it][0];
                float gf = g_s[(32 + c)  * 16 + m] + breg[it][1];
                float gg = g_s[(64 + c)  * 16 + m] + breg[it][2];
                float go = g_s[(96 + c)  * 16 + m] + breg[it][3];
                float cn = sigf(gf) * cst[it] + sigf(gi) * tanhfast(gg);
                float h  = sigf(go) * tanhfast(cn);
                cst[it] = cn;
                unsigned short hh = f2bf(h);
                unsigned short hl = f2bf(h - bf2f(hh));
                int off = frag_off(m, c);
                hA_hi[off] = (short)hh;
                hA_lo[off] = (short)hl;
                y2[((size_t)(b0 + m) * Tz + t) * 42 + dir * H2 + c] = hh;
            }
        }
        // write staged x for next step
        if (hx) {
#pragma unroll
            for (int i = 0; i < 5; ++i) {
                int e2 = tid + 256 * i;
                if (e2 < 1120) {
                    int m = e2 / 70, xip = e2 % 70;
                    int k = 32 + 2 * xip;
                    ((unsigned int*)hA_hi)[frag_off(m, k) >> 1] = xr[i];
                }
            }
        }
    }
}

// ---------------------------------------------------------------------------
// Dense head: thread per (b,t), unchanged (passing, ~25 us).
// ---------------------------------------------------------------------------
__global__ __launch_bounds__(256) void k_dense(
    const unsigned short* __restrict__ y2,
    const float* __restrict__ wd1, const float* __restrict__ bd1,
    const float* __restrict__ wd2, const float* __restrict__ bd2,
    const float* __restrict__ wo,  const float* __restrict__ bo,
    float* __restrict__ out)
{
    int idx = blockIdx.x * 256 + threadIdx.x;
    if (idx >= Bz * Tz) return;
    const unsigned int* row = (const unsigned int*)&y2[(size_t)idx * 42];

    float v[42];
#pragma unroll
    for (int j = 0; j < 21; ++j) {
        unsigned int p = row[j];
        v[2 * j]     = bf2f((unsigned short)(p & 0xFFFFu));
        v[2 * j + 1] = bf2f((unsigned short)(p >> 16));
    }

    float h1[30];
#pragma unroll
    for (int o = 0; o < 30; ++o) {
        float s = bd1[o];
#pragma unroll
        for (int j = 0; j < 42; ++j) s = fmaf(v[j], wd1[o * 42 + j], s);
        h1[o] = fmaxf(s, 0.0f);
    }
    float outv = bo[0];
#pragma unroll
    for (int o = 0; o < 20; ++o) {
        float s = bd2[o];
#pragma unroll
        for (int j = 0; j < 30; ++j) s = fmaf(h1[j], wd2[o * 30 + j], s);
        outv = fmaf(fmaxf(s, 0.0f), wo[o], outv);
    }
    out[idx] = outv;
}

// ---------------------------------------------------------------------------
extern "C" void kernel_launch(void* const* d_in, const int* in_sizes, int n_in,
                              void* d_out, int out_size, void* d_ws, size_t ws_size,
                              hipStream_t stream)
{
    const float* x      = (const float*)d_in[0];
    const float* w1f_ih = (const float*)d_in[1];
    const float* w1f_hh = (const float*)d_in[2];
    const float* b1f_ih = (const float*)d_in[3];
    const float* b1f_hh = (const float*)d_in[4];
    const float* w1b_ih = (const float*)d_in[5];
    const float* w1b_hh = (const float*)d_in[6];
    const float* b1b_ih = (const float*)d_in[7];
    const float* b1b_hh = (const float*)d_in[8];
    const float* w2f_ih = (const float*)d_in[9];
    const float* w2f_hh = (const float*)d_in[10];
    const float* b2f_ih = (const float*)d_in[11];
    const float* b2f_hh = (const float*)d_in[12];
    const float* w2b_ih = (const float*)d_in[13];
    const float* w2b_hh = (const float*)d_in[14];
    const float* b2b_ih = (const float*)d_in[15];
    const float* b2b_hh = (const float*)d_in[16];
    const float* wd1    = (const float*)d_in[17];
    const float* bd1    = (const float*)d_in[18];
    const float* wd2    = (const float*)d_in[19];
    const float* bd2    = (const float*)d_in[20];
    const float* wo     = (const float*)d_in[21];
    const float* bo     = (const float*)d_in[22];
    float* out = (float*)d_out;

    // Workspace: y1 bf16 [T][B][140] (192.7 MB) + y2 bf16 [B][T][42] (57.8 MB)
    const size_t y1_elems = (size_t)Tz * Bz * 140;
    const size_t y2_elems = (size_t)Bz * Tz * 42;
    if (ws_size < (y1_elems + y2_elems) * 2) return;

    unsigned short* y1 = (unsigned short*)d_ws;
    unsigned short* y2 = y1 + y1_elems;

    hipLaunchKernelGGL(k_lstm1, dim3(256), dim3(256), 0, stream,
                       x, w1f_ih, w1f_hh, b1f_ih, b1f_hh,
                       w1b_ih, w1b_hh, b1b_ih, b1b_hh, y1);
    hipLaunchKernelGGL(k_lstm2, dim3(256), dim3(256), 0, stream,
                       y1, w2f_ih, w2f_hh, b2f_ih, b2f_hh,
                       w2b_ih, w2b_hh, b2b_ih, b2b_hh, y2);
    hipLaunchKernelGGL(k_dense, dim3((Bz * Tz + 255) / 256), dim3(256), 0, stream,
                       y2, wd1, bd1, wd2, bd2, wo, bo, out);
}